// Round 3
// baseline (911.987 us; speedup 1.0000x reference)
//
#include <hip/hip_runtime.h>
#include <math.h>

#define NN 50000
#define NE 800000
#define HEADS 4
#define HID 64
#define HD 256          // HEADS*HID flattened feature dim
#define NEG_SLOPE 0.2f
#define NCHUNK 49       // ceil(50000/1024)

// ---------------- CSR build ----------------
__global__ void count_kernel(const int* __restrict__ dst, int* __restrict__ cnt) {
    int e = blockIdx.x * 256 + threadIdx.x;
    if (e < NE) atomicAdd(&cnt[dst[e]], 1);
}

__global__ void chunk_sum_kernel(const int* __restrict__ cnt, int* __restrict__ csum, int n) {
    __shared__ int sdata[256];
    int base = blockIdx.x * 1024;
    int t = threadIdx.x;
    int s = 0;
    for (int i = t; i < 1024; i += 256) {
        int idx = base + i;
        if (idx < n) s += cnt[idx];
    }
    sdata[t] = s; __syncthreads();
    for (int off = 128; off > 0; off >>= 1) {
        if (t < off) sdata[t] += sdata[t + off];
        __syncthreads();
    }
    if (t == 0) csum[blockIdx.x] = sdata[0];
}

__global__ void chunk_scan_kernel(int* __restrict__ csum, int nchunks) {
    if (threadIdx.x == 0 && blockIdx.x == 0) {
        int run = 0;
        for (int i = 0; i < nchunks; i++) { int v = csum[i]; csum[i] = run; run += v; }
    }
}

__global__ void rowptr_kernel(const int* __restrict__ cnt, const int* __restrict__ coff,
                              int* __restrict__ rowptr, int n) {
    __shared__ int buf[1024];
    int t = threadIdx.x;
    int idx = blockIdx.x * 1024 + t;
    int v = (idx < n) ? cnt[idx] : 0;
    buf[t] = v; __syncthreads();
    for (int off = 1; off < 1024; off <<= 1) {
        int tmp = (t >= off) ? buf[t - off] : 0;
        __syncthreads();
        buf[t] += tmp;
        __syncthreads();
    }
    int excl = buf[t] - v + coff[blockIdx.x];
    if (idx < n) rowptr[idx] = excl;
    if (idx == n - 1) rowptr[n] = excl + v;
}

__global__ void scatter_kernel(const int* __restrict__ src, const int* __restrict__ dst,
                               const int* __restrict__ rowptr, int* __restrict__ cursor,
                               int* __restrict__ csr_src) {
    int e = blockIdx.x * 256 + threadIdx.x;
    if (e < NE) {
        int d = dst[e];
        int p = rowptr[d] + atomicAdd(&cursor[d], 1);
        csr_src[p] = src[e];
    }
}

// sort each node's src list ascending (L2 temporal locality during gather)
__global__ void sort_kernel(const int* __restrict__ rowptr, int* __restrict__ csr_src) {
    int v = blockIdx.x * 256 + threadIdx.x;
    if (v >= NN) return;
    int beg = rowptr[v], end = rowptr[v + 1];
    for (int i = beg + 1; i < end; i++) {
        int key = csr_src[i];
        int j = i - 1;
        while (j >= beg && csr_src[j] > key) { csr_src[j + 1] = csr_src[j]; j--; }
        csr_src[j + 1] = key;
    }
}

// ---------------- SGEMM: H[N,256] = X[N,K] @ W[K,256] ----------------
// 128x128 block tile, 8x8 microtile in split 4+4 row/col groups.
__global__ __launch_bounds__(256) void sgemm_kernel(const float* __restrict__ X,
                                                    const float* __restrict__ W,
                                                    float* __restrict__ H, int K) {
    __shared__ float As[16][128];
    __shared__ float Bs[16][128];
    int tid = threadIdx.x;
    int rowBase = blockIdx.x * 128;
    int n0 = blockIdx.y * 128;
    float acc[8][8] = {};

    int ar = tid >> 1, kh = (tid & 1) * 8;   // A: row ar (0..127), k-half kh
    int bk = tid >> 4, bn = (tid & 15) * 8;  // B: k row bk (0..15), col oct bn
    int tx = (tid & 15) * 4;                 // rows tx..tx+3 and 64+tx..64+tx+3
    int ty = (tid >> 4) * 4;                 // cols ty..ty+3 and 64+ty..64+ty+3

    for (int k0 = 0; k0 < K; k0 += 16) {
        float4 a0 = make_float4(0.f, 0.f, 0.f, 0.f);
        float4 a1 = make_float4(0.f, 0.f, 0.f, 0.f);
        int arow = rowBase + ar;
        if (arow < NN) {
            const float* xp = &X[(long)arow * K + k0 + kh];
            a0 = *(const float4*)xp;
            a1 = *(const float4*)(xp + 4);
        }
        As[kh + 0][ar] = a0.x; As[kh + 1][ar] = a0.y;
        As[kh + 2][ar] = a0.z; As[kh + 3][ar] = a0.w;
        As[kh + 4][ar] = a1.x; As[kh + 5][ar] = a1.y;
        As[kh + 6][ar] = a1.z; As[kh + 7][ar] = a1.w;
        const float* wp = &W[(long)(k0 + bk) * HD + n0 + bn];
        *(float4*)&Bs[bk][bn]     = *(const float4*)wp;
        *(float4*)&Bs[bk][bn + 4] = *(const float4*)(wp + 4);
        __syncthreads();
#pragma unroll
        for (int kk = 0; kk < 16; kk++) {
            float4 aA = *(const float4*)&As[kk][tx];
            float4 aB = *(const float4*)&As[kk][64 + tx];
            float4 bA = *(const float4*)&Bs[kk][ty];
            float4 bB = *(const float4*)&Bs[kk][64 + ty];
            float av[8] = {aA.x, aA.y, aA.z, aA.w, aB.x, aB.y, aB.z, aB.w};
            float bv[8] = {bA.x, bA.y, bA.z, bA.w, bB.x, bB.y, bB.z, bB.w};
#pragma unroll
            for (int i = 0; i < 8; i++)
#pragma unroll
                for (int j = 0; j < 8; j++) acc[i][j] += av[i] * bv[j];
        }
        __syncthreads();
    }
#pragma unroll
    for (int g = 0; g < 2; g++) {
#pragma unroll
        for (int i = 0; i < 4; i++) {
            int r = rowBase + g * 64 + tx + i;
            if (r < NN) {
                int ii = g * 4 + i;
                float4 o0 = make_float4(acc[ii][0], acc[ii][1], acc[ii][2], acc[ii][3]);
                float4 o1 = make_float4(acc[ii][4], acc[ii][5], acc[ii][6], acc[ii][7]);
                *(float4*)&H[(long)r * HD + n0 + ty] = o0;
                *(float4*)&H[(long)r * HD + n0 + 64 + ty] = o1;
            }
        }
    }
}

// ---------------- el/er: one wave per node ----------------
__global__ __launch_bounds__(256) void el_er_kernel(const float* __restrict__ H,
                                                    const float* __restrict__ al,
                                                    const float* __restrict__ ar,
                                                    float* __restrict__ el,
                                                    float* __restrict__ er) {
    int wave = threadIdx.x >> 6, lane = threadIdx.x & 63;
    int n = blockIdx.x * 4 + wave;
    if (n >= NN) return;
    float4 h4 = *(const float4*)&H[(long)n * HD + lane * 4];
    float4 a4 = *(const float4*)&al[lane * 4];
    float4 r4 = *(const float4*)&ar[lane * 4];
    float pl = h4.x * a4.x + h4.y * a4.y + h4.z * a4.z + h4.w * a4.w;
    float pr = h4.x * r4.x + h4.y * r4.y + h4.z * r4.z + h4.w * r4.w;
#pragma unroll
    for (int off = 1; off < 16; off <<= 1) {
        pl += __shfl_xor(pl, off);
        pr += __shfl_xor(pr, off);
    }
    if ((lane & 15) == 0) {
        el[n * 4 + (lane >> 4)] = pl;
        er[n * 4 + (lane >> 4)] = pr;
    }
}

// ---------------- GAT per-node: single-pass flash softmax, unroll-4 ----------------
__device__ __forceinline__ float lrelu(float x) { return x > 0.f ? x : NEG_SLOPE * x; }

template <int FINAL>
__global__ __launch_bounds__(256) void gat_node_kernel(
    const float* __restrict__ H, const float* __restrict__ el, const float* __restrict__ er,
    const int* __restrict__ rowptr, const int* __restrict__ csr_src,
    float* __restrict__ out, const float* __restrict__ Wout, const float* __restrict__ bout,
    float* __restrict__ final_out) {
    int wave = threadIdx.x >> 6, lane = threadIdx.x & 63;
    int v = blockIdx.x * 4 + wave;
    if (v >= NN) return;
    int beg = rowptr[v], end = rowptr[v + 1];

    int hh = lane >> 4;                    // head for this lane's feature slice
    float er_h = er[v * 4 + hh];

    float m = -INFINITY;
    float ssum = 0.f;
    float4 acc = make_float4(0.f, 0.f, 0.f, 0.f);

    for (int base = beg; base < end; base += 4) {
        int i1 = base + 1 < end ? base + 1 : end - 1;
        int i2 = base + 2 < end ? base + 2 : end - 1;
        int i3 = base + 3 < end ? base + 3 : end - 1;
        int s0 = csr_src[base];
        int s1 = csr_src[i1];
        int s2 = csr_src[i2];
        int s3 = csr_src[i3];
        float el0 = el[s0 * 4 + hh];
        float el1 = el[s1 * 4 + hh];
        float el2 = el[s2 * 4 + hh];
        float el3 = el[s3 * 4 + hh];
        float4 h0 = *(const float4*)&H[(long)s0 * HD + lane * 4];
        float4 h1 = *(const float4*)&H[(long)s1 * HD + lane * 4];
        float4 h2 = *(const float4*)&H[(long)s2 * HD + lane * 4];
        float4 h3 = *(const float4*)&H[(long)s3 * HD + lane * 4];
        float e0 = lrelu(el0 + er_h);
        float e1 = (base + 1 < end) ? lrelu(el1 + er_h) : -INFINITY;
        float e2 = (base + 2 < end) ? lrelu(el2 + er_h) : -INFINITY;
        float e3 = (base + 3 < end) ? lrelu(el3 + er_h) : -INFINITY;
        float mn = fmaxf(fmaxf(m, fmaxf(e0, e1)), fmaxf(e2, e3));
        float sc = __expf(m - mn);
        float w0 = __expf(e0 - mn);
        float w1 = __expf(e1 - mn);
        float w2 = __expf(e2 - mn);
        float w3 = __expf(e3 - mn);
        ssum = ssum * sc + w0 + w1 + w2 + w3;
        acc.x = acc.x * sc + w0 * h0.x + w1 * h1.x + w2 * h2.x + w3 * h3.x;
        acc.y = acc.y * sc + w0 * h0.y + w1 * h1.y + w2 * h2.y + w3 * h3.y;
        acc.z = acc.z * sc + w0 * h0.z + w1 * h1.z + w2 * h2.z + w3 * h3.z;
        acc.w = acc.w * sc + w0 * h0.w + w1 * h1.w + w2 * h2.w + w3 * h3.w;
        m = mn;
    }

    float inv = 1.0f / (ssum + 1e-9f);
    acc.x *= inv; acc.y *= inv; acc.z *= inv; acc.w *= inv;

    // elu
    acc.x = acc.x > 0.f ? acc.x : expm1f(acc.x);
    acc.y = acc.y > 0.f ? acc.y : expm1f(acc.y);
    acc.z = acc.z > 0.f ? acc.z : expm1f(acc.z);
    acc.w = acc.w > 0.f ? acc.w : expm1f(acc.w);

    if (!FINAL) {
        *(float4*)&out[(long)v * HD + lane * 4] = acc;
    } else {
        // mean over heads (lanes l, l^16, l^32 hold same d-range, different head)
        acc.x += __shfl_xor(acc.x, 16); acc.x += __shfl_xor(acc.x, 32);
        acc.y += __shfl_xor(acc.y, 16); acc.y += __shfl_xor(acc.y, 32);
        acc.z += __shfl_xor(acc.z, 16); acc.z += __shfl_xor(acc.z, 32);
        acc.w += __shfl_xor(acc.w, 16); acc.w += __shfl_xor(acc.w, 32);
        float4 w4 = *(const float4*)&Wout[(lane & 15) * 4];
        float p = 0.25f * (acc.x * w4.x + acc.y * w4.y + acc.z * w4.z + acc.w * w4.w);
        p += __shfl_xor(p, 1);
        p += __shfl_xor(p, 2);
        p += __shfl_xor(p, 4);
        p += __shfl_xor(p, 8);
        if (lane == 0) final_out[v] = fmaxf(p + bout[0], 0.f);
    }
}

extern "C" void kernel_launch(void* const* d_in, const int* in_sizes, int n_in,
                              void* d_out, int out_size, void* d_ws, size_t ws_size,
                              hipStream_t stream) {
    const float* x    = (const float*)d_in[0];
    const int*   src  = (const int*)d_in[1];
    const int*   dst  = (const int*)d_in[2];
    const float* W0   = (const float*)d_in[3];
    const float* al0  = (const float*)d_in[4];
    const float* ar0  = (const float*)d_in[5];
    const float* W1   = (const float*)d_in[6];
    const float* al1  = (const float*)d_in[7];
    const float* ar1  = (const float*)d_in[8];
    const float* W2   = (const float*)d_in[9];
    const float* al2  = (const float*)d_in[10];
    const float* ar2  = (const float*)d_in[11];
    const float* Wout = (const float*)d_in[12];
    const float* bout = (const float*)d_in[13];
    float* outp = (float*)d_out;

    char* ws = (char*)d_ws;
    size_t off = 0;
    auto carve = [&](size_t n) -> char* {
        char* p = ws + off;
        off += (n + 255) & ~(size_t)255;
        return p;
    };
    float* h_buf   = (float*)carve((size_t)NN * HD * 4);
    float* x_buf   = (float*)carve((size_t)NN * HD * 4);
    float* el      = (float*)carve((size_t)NN * HEADS * 4);
    float* er      = (float*)carve((size_t)NN * HEADS * 4);
    int*   cnt     = (int*)carve((size_t)NN * 4);
    int*   rowptr  = (int*)carve((size_t)(NN + 1) * 4);
    int*   csr_src = (int*)carve((size_t)NE * 4);
    int*   csum    = (int*)carve(64 * 4);

    // ---- build dst-CSR (same work every call) ----
    hipMemsetAsync(cnt, 0, (size_t)NN * 4, stream);
    count_kernel<<<(NE + 255) / 256, 256, 0, stream>>>(dst, cnt);
    chunk_sum_kernel<<<NCHUNK, 256, 0, stream>>>(cnt, csum, NN);
    chunk_scan_kernel<<<1, 64, 0, stream>>>(csum, NCHUNK);
    rowptr_kernel<<<NCHUNK, 1024, 0, stream>>>(cnt, csum, rowptr, NN);
    hipMemsetAsync(cnt, 0, (size_t)NN * 4, stream);
    scatter_kernel<<<(NE + 255) / 256, 256, 0, stream>>>(src, dst, rowptr, cnt, csr_src);
    sort_kernel<<<(NN + 255) / 256, 256, 0, stream>>>(rowptr, csr_src);

    dim3 gGemm((NN + 127) / 128, HD / 128);
    int gNode = (NN + 3) / 4;

    // ---- layer 0 ----
    sgemm_kernel<<<gGemm, 256, 0, stream>>>(x, W0, h_buf, 128);
    el_er_kernel<<<gNode, 256, 0, stream>>>(h_buf, al0, ar0, el, er);
    gat_node_kernel<0><<<gNode, 256, 0, stream>>>(h_buf, el, er, rowptr, csr_src,
                                                  x_buf, nullptr, nullptr, nullptr);
    // ---- layer 1 ----
    sgemm_kernel<<<gGemm, 256, 0, stream>>>(x_buf, W1, h_buf, 256);
    el_er_kernel<<<gNode, 256, 0, stream>>>(h_buf, al1, ar1, el, er);
    gat_node_kernel<0><<<gNode, 256, 0, stream>>>(h_buf, el, er, rowptr, csr_src,
                                                  x_buf, nullptr, nullptr, nullptr);
    // ---- layer 2 (final: fused elu + head-mean + Wout + relu) ----
    sgemm_kernel<<<gGemm, 256, 0, stream>>>(x_buf, W2, h_buf, 256);
    el_er_kernel<<<gNode, 256, 0, stream>>>(h_buf, al2, ar2, el, er);
    gat_node_kernel<1><<<gNode, 256, 0, stream>>>(h_buf, el, er, rowptr, csr_src,
                                                  nullptr, Wout, bout, outp);
}

// Round 4
// 899.661 us; speedup vs baseline: 1.0137x; 1.0137x over previous
//
#include <hip/hip_runtime.h>
#include <math.h>

#define NN 50000
#define NE 800000
#define HEADS 4
#define HID 64
#define HD 256          // HEADS*HID flattened feature dim
#define NEG_SLOPE 0.2f
#define NCHUNK 49       // ceil(50000/1024)

// ---------------- CSR build ----------------
__global__ void count_kernel(const int* __restrict__ dst, int* __restrict__ cnt) {
    int e = blockIdx.x * 256 + threadIdx.x;
    if (e < NE) atomicAdd(&cnt[dst[e]], 1);
}

__global__ void chunk_sum_kernel(const int* __restrict__ cnt, int* __restrict__ csum, int n) {
    __shared__ int sdata[256];
    int base = blockIdx.x * 1024;
    int t = threadIdx.x;
    int s = 0;
    for (int i = t; i < 1024; i += 256) {
        int idx = base + i;
        if (idx < n) s += cnt[idx];
    }
    sdata[t] = s; __syncthreads();
    for (int off = 128; off > 0; off >>= 1) {
        if (t < off) sdata[t] += sdata[t + off];
        __syncthreads();
    }
    if (t == 0) csum[blockIdx.x] = sdata[0];
}

__global__ void chunk_scan_kernel(int* __restrict__ csum, int nchunks) {
    if (threadIdx.x == 0 && blockIdx.x == 0) {
        int run = 0;
        for (int i = 0; i < nchunks; i++) { int v = csum[i]; csum[i] = run; run += v; }
    }
}

__global__ void rowptr_kernel(const int* __restrict__ cnt, const int* __restrict__ coff,
                              int* __restrict__ rowptr, int n) {
    __shared__ int buf[1024];
    int t = threadIdx.x;
    int idx = blockIdx.x * 1024 + t;
    int v = (idx < n) ? cnt[idx] : 0;
    buf[t] = v; __syncthreads();
    for (int off = 1; off < 1024; off <<= 1) {
        int tmp = (t >= off) ? buf[t - off] : 0;
        __syncthreads();
        buf[t] += tmp;
        __syncthreads();
    }
    int excl = buf[t] - v + coff[blockIdx.x];
    if (idx < n) rowptr[idx] = excl;
    if (idx == n - 1) rowptr[n] = excl + v;
}

__global__ void scatter_kernel(const int* __restrict__ src, const int* __restrict__ dst,
                               const int* __restrict__ rowptr, int* __restrict__ cursor,
                               int* __restrict__ csr_src) {
    int e = blockIdx.x * 256 + threadIdx.x;
    if (e < NE) {
        int d = dst[e];
        int p = rowptr[d] + atomicAdd(&cursor[d], 1);
        csr_src[p] = src[e];
    }
}

// ---------------- SGEMM + fused el/er: H[N,256] = X[N,K] @ W[K,256] ----------------
// 128x128 tile, 8x8 microtile, register-prefetch pipeline.
// Epilogue computes el/er partials (dot with al/ar) and stores them exclusively:
// block (bx,by) owns rows bx*128.. and heads {2*by, 2*by+1}.
__global__ __launch_bounds__(256) void sgemm_el_kernel(
    const float* __restrict__ X, const float* __restrict__ W, float* __restrict__ H, int K,
    const float* __restrict__ al, const float* __restrict__ ar,
    float* __restrict__ el, float* __restrict__ er) {
    __shared__ float As[16][128];
    __shared__ float Bs[16][128];
    __shared__ float red[4][128][4];
    int tid = threadIdx.x;
    int lane = tid & 63, wv = tid >> 6;
    int rowBase = blockIdx.x * 128;
    int n0 = blockIdx.y * 128;
    float acc[8][8] = {};

    int arr = tid >> 1, kh = (tid & 1) * 8;  // A: row arr (0..127), k-half kh
    int bk = tid >> 4, bn = (tid & 15) * 8;  // B: k row bk (0..15), col oct bn
    int tx = (tid & 15) * 4;                 // rows tx..tx+3 and 64+tx..64+tx+3
    int ty = (tid >> 4) * 4;                 // cols ty..ty+3 and 64+ty..64+ty+3

    int arow = rowBase + arr;
    const float* xp = &X[(long)arow * K + kh];

    float4 a0 = make_float4(0.f, 0.f, 0.f, 0.f);
    float4 a1 = make_float4(0.f, 0.f, 0.f, 0.f);
    if (arow < NN) { a0 = *(const float4*)xp; a1 = *(const float4*)(xp + 4); }
    const float* wp0 = &W[(long)bk * HD + n0 + bn];
    float4 b0 = *(const float4*)wp0;
    float4 b1 = *(const float4*)(wp0 + 4);

    for (int k0 = 0; k0 < K; k0 += 16) {
        As[kh + 0][arr] = a0.x; As[kh + 1][arr] = a0.y;
        As[kh + 2][arr] = a0.z; As[kh + 3][arr] = a0.w;
        As[kh + 4][arr] = a1.x; As[kh + 5][arr] = a1.y;
        As[kh + 6][arr] = a1.z; As[kh + 7][arr] = a1.w;
        *(float4*)&Bs[bk][bn]     = b0;
        *(float4*)&Bs[bk][bn + 4] = b1;
        __syncthreads();
        if (k0 + 16 < K) {    // prefetch next tile into regs; overlaps compute below
            if (arow < NN) {
                const float* xn = xp + k0 + 16;
                a0 = *(const float4*)xn;
                a1 = *(const float4*)(xn + 4);
            }
            const float* wn = &W[(long)(k0 + 16 + bk) * HD + n0 + bn];
            b0 = *(const float4*)wn;
            b1 = *(const float4*)(wn + 4);
        }
#pragma unroll
        for (int kk = 0; kk < 16; kk++) {
            float4 aA = *(const float4*)&As[kk][tx];
            float4 aB = *(const float4*)&As[kk][64 + tx];
            float4 bA = *(const float4*)&Bs[kk][ty];
            float4 bB = *(const float4*)&Bs[kk][64 + ty];
            float av[8] = {aA.x, aA.y, aA.z, aA.w, aB.x, aB.y, aB.z, aB.w};
            float bv[8] = {bA.x, bA.y, bA.z, bA.w, bB.x, bB.y, bB.z, bB.w};
#pragma unroll
            for (int i = 0; i < 8; i++)
#pragma unroll
                for (int j = 0; j < 8; j++) acc[i][j] += av[i] * bv[j];
        }
        __syncthreads();
    }

    // ---- store H tile ----
#pragma unroll
    for (int g = 0; g < 2; g++) {
#pragma unroll
        for (int i = 0; i < 4; i++) {
            int r = rowBase + g * 64 + tx + i;
            if (r < NN) {
                int ii = g * 4 + i;
                float4 o0 = make_float4(acc[ii][0], acc[ii][1], acc[ii][2], acc[ii][3]);
                float4 o1 = make_float4(acc[ii][4], acc[ii][5], acc[ii][6], acc[ii][7]);
                *(float4*)&H[(long)r * HD + n0 + ty] = o0;
                *(float4*)&H[(long)r * HD + n0 + 64 + ty] = o1;
            }
        }
    }

    // ---- fused el/er partials ----
    float4 alA = *(const float4*)&al[n0 + ty];
    float4 alB = *(const float4*)&al[n0 + 64 + ty];
    float4 arA = *(const float4*)&ar[n0 + ty];
    float4 arB = *(const float4*)&ar[n0 + 64 + ty];
#pragma unroll
    for (int i = 0; i < 8; i++) {
        float s0 = acc[i][0] * alA.x + acc[i][1] * alA.y + acc[i][2] * alA.z + acc[i][3] * alA.w;
        float s1 = acc[i][4] * alB.x + acc[i][5] * alB.y + acc[i][6] * alB.z + acc[i][7] * alB.w;
        float t0 = acc[i][0] * arA.x + acc[i][1] * arA.y + acc[i][2] * arA.z + acc[i][3] * arA.w;
        float t1 = acc[i][4] * arB.x + acc[i][5] * arB.y + acc[i][6] * arB.z + acc[i][7] * arB.w;
        s0 += __shfl_xor(s0, 16); s0 += __shfl_xor(s0, 32);
        s1 += __shfl_xor(s1, 16); s1 += __shfl_xor(s1, 32);
        t0 += __shfl_xor(t0, 16); t0 += __shfl_xor(t0, 32);
        t1 += __shfl_xor(t1, 16); t1 += __shfl_xor(t1, 32);
        if (lane < 16) {
            int r = (i < 4) ? (tx + i) : (64 + tx + i - 4);
            red[wv][r][0] = s0; red[wv][r][1] = s1;
            red[wv][r][2] = t0; red[wv][r][3] = t1;
        }
    }
    __syncthreads();
#pragma unroll
    for (int v = 0; v < 2; v++) {
        int fv = tid + v * 256;
        int r = fv >> 2, k = fv & 3;
        float s = red[0][r][k] + red[1][r][k] + red[2][r][k] + red[3][r][k];
        int gr = rowBase + r;
        if (gr < NN) {
            int hidx = (n0 >> 6) + (k & 1);
            if (k < 2) el[gr * 4 + hidx] = s;
            else       er[gr * 4 + hidx] = s;
        }
    }
}

// ---------------- GAT per-node: single-pass flash softmax, unroll-2 ----------------
__device__ __forceinline__ float lrelu(float x) { return x > 0.f ? x : NEG_SLOPE * x; }

template <int FINAL>
__global__ __launch_bounds__(256) void gat_node_kernel(
    const float* __restrict__ H, const float* __restrict__ el, const float* __restrict__ er,
    const int* __restrict__ rowptr, const int* __restrict__ csr_src,
    float* __restrict__ out, const float* __restrict__ Wout, const float* __restrict__ bout,
    float* __restrict__ final_out) {
    int wave = threadIdx.x >> 6, lane = threadIdx.x & 63;
    int v = blockIdx.x * 4 + wave;
    if (v >= NN) return;
    int beg = rowptr[v], end = rowptr[v + 1];

    int hh = lane >> 4;                    // head for this lane's feature slice
    float er_h = er[v * 4 + hh];

    float m = -INFINITY;
    float ssum = 0.f;
    float4 acc = make_float4(0.f, 0.f, 0.f, 0.f);

    int idx = beg;
    for (; idx + 2 <= end; idx += 2) {
        int s0 = csr_src[idx];
        int s1 = csr_src[idx + 1];
        float el0 = el[s0 * 4 + hh];
        float el1 = el[s1 * 4 + hh];
        float4 h0 = *(const float4*)&H[(long)s0 * HD + lane * 4];
        float4 h1 = *(const float4*)&H[(long)s1 * HD + lane * 4];
        float e0 = lrelu(el0 + er_h);
        float e1 = lrelu(el1 + er_h);
        float mn = fmaxf(m, fmaxf(e0, e1));
        float sc = __expf(m - mn);
        float w0 = __expf(e0 - mn);
        float w1 = __expf(e1 - mn);
        ssum = ssum * sc + w0 + w1;
        acc.x = acc.x * sc + w0 * h0.x + w1 * h1.x;
        acc.y = acc.y * sc + w0 * h0.y + w1 * h1.y;
        acc.z = acc.z * sc + w0 * h0.z + w1 * h1.z;
        acc.w = acc.w * sc + w0 * h0.w + w1 * h1.w;
        m = mn;
    }
    if (idx < end) {
        int s0 = csr_src[idx];
        float el0 = el[s0 * 4 + hh];
        float4 h0 = *(const float4*)&H[(long)s0 * HD + lane * 4];
        float e0 = lrelu(el0 + er_h);
        float mn = fmaxf(m, e0);
        float sc = __expf(m - mn);
        float w0 = __expf(e0 - mn);
        ssum = ssum * sc + w0;
        acc.x = acc.x * sc + w0 * h0.x;
        acc.y = acc.y * sc + w0 * h0.y;
        acc.z = acc.z * sc + w0 * h0.z;
        acc.w = acc.w * sc + w0 * h0.w;
    }

    float inv = 1.0f / (ssum + 1e-9f);
    acc.x *= inv; acc.y *= inv; acc.z *= inv; acc.w *= inv;

    // elu
    acc.x = acc.x > 0.f ? acc.x : expm1f(acc.x);
    acc.y = acc.y > 0.f ? acc.y : expm1f(acc.y);
    acc.z = acc.z > 0.f ? acc.z : expm1f(acc.z);
    acc.w = acc.w > 0.f ? acc.w : expm1f(acc.w);

    if (!FINAL) {
        *(float4*)&out[(long)v * HD + lane * 4] = acc;
    } else {
        // mean over heads (lanes l, l^16, l^32 hold same d-range, different head)
        acc.x += __shfl_xor(acc.x, 16); acc.x += __shfl_xor(acc.x, 32);
        acc.y += __shfl_xor(acc.y, 16); acc.y += __shfl_xor(acc.y, 32);
        acc.z += __shfl_xor(acc.z, 16); acc.z += __shfl_xor(acc.z, 32);
        acc.w += __shfl_xor(acc.w, 16); acc.w += __shfl_xor(acc.w, 32);
        float4 w4 = *(const float4*)&Wout[(lane & 15) * 4];
        float p = 0.25f * (acc.x * w4.x + acc.y * w4.y + acc.z * w4.z + acc.w * w4.w);
        p += __shfl_xor(p, 1);
        p += __shfl_xor(p, 2);
        p += __shfl_xor(p, 4);
        p += __shfl_xor(p, 8);
        if (lane == 0) final_out[v] = fmaxf(p + bout[0], 0.f);
    }
}

extern "C" void kernel_launch(void* const* d_in, const int* in_sizes, int n_in,
                              void* d_out, int out_size, void* d_ws, size_t ws_size,
                              hipStream_t stream) {
    const float* x    = (const float*)d_in[0];
    const int*   src  = (const int*)d_in[1];
    const int*   dst  = (const int*)d_in[2];
    const float* W0   = (const float*)d_in[3];
    const float* al0  = (const float*)d_in[4];
    const float* ar0  = (const float*)d_in[5];
    const float* W1   = (const float*)d_in[6];
    const float* al1  = (const float*)d_in[7];
    const float* ar1  = (const float*)d_in[8];
    const float* W2   = (const float*)d_in[9];
    const float* al2  = (const float*)d_in[10];
    const float* ar2  = (const float*)d_in[11];
    const float* Wout = (const float*)d_in[12];
    const float* bout = (const float*)d_in[13];
    float* outp = (float*)d_out;

    char* ws = (char*)d_ws;
    size_t off = 0;
    auto carve = [&](size_t n) -> char* {
        char* p = ws + off;
        off += (n + 255) & ~(size_t)255;
        return p;
    };
    float* h_buf   = (float*)carve((size_t)NN * HD * 4);
    float* x_buf   = (float*)carve((size_t)NN * HD * 4);
    float* el      = (float*)carve((size_t)NN * HEADS * 4);
    float* er      = (float*)carve((size_t)NN * HEADS * 4);
    int*   cnt     = (int*)carve((size_t)NN * 4);
    int*   rowptr  = (int*)carve((size_t)(NN + 1) * 4);
    int*   csr_src = (int*)carve((size_t)NE * 4);
    int*   csum    = (int*)carve(64 * 4);

    // ---- build dst-CSR (same work every call) ----
    hipMemsetAsync(cnt, 0, (size_t)NN * 4, stream);
    count_kernel<<<(NE + 255) / 256, 256, 0, stream>>>(dst, cnt);
    chunk_sum_kernel<<<NCHUNK, 256, 0, stream>>>(cnt, csum, NN);
    chunk_scan_kernel<<<1, 64, 0, stream>>>(csum, NCHUNK);
    rowptr_kernel<<<NCHUNK, 1024, 0, stream>>>(cnt, csum, rowptr, NN);
    hipMemsetAsync(cnt, 0, (size_t)NN * 4, stream);
    scatter_kernel<<<(NE + 255) / 256, 256, 0, stream>>>(src, dst, rowptr, cnt, csr_src);

    dim3 gGemm((NN + 127) / 128, HD / 128);
    int gNode = (NN + 3) / 4;

    // ---- layer 0 ----
    sgemm_el_kernel<<<gGemm, 256, 0, stream>>>(x, W0, h_buf, 128, al0, ar0, el, er);
    gat_node_kernel<0><<<gNode, 256, 0, stream>>>(h_buf, el, er, rowptr, csr_src,
                                                  x_buf, nullptr, nullptr, nullptr);
    // ---- layer 1 ----
    sgemm_el_kernel<<<gGemm, 256, 0, stream>>>(x_buf, W1, h_buf, 256, al1, ar1, el, er);
    gat_node_kernel<0><<<gNode, 256, 0, stream>>>(h_buf, el, er, rowptr, csr_src,
                                                  x_buf, nullptr, nullptr, nullptr);
    // ---- layer 2 (final: fused elu + head-mean + Wout + relu) ----
    sgemm_el_kernel<<<gGemm, 256, 0, stream>>>(x_buf, W2, h_buf, 256, al2, ar2, el, er);
    gat_node_kernel<1><<<gNode, 256, 0, stream>>>(h_buf, el, er, rowptr, csr_src,
                                                  nullptr, Wout, bout, outp);
}

// Round 5
// 775.414 us; speedup vs baseline: 1.1761x; 1.1602x over previous
//
#include <hip/hip_runtime.h>
#include <math.h>

#define NN 50000
#define NE 800000
#define HEADS 4
#define HID 64
#define HD 256          // HEADS*HID flattened feature dim
#define NEG_SLOPE 0.2f
#define NCHUNK 49       // ceil(50000/1024)

typedef __attribute__((ext_vector_type(8))) short short8;
typedef __attribute__((ext_vector_type(4))) float f32x4;

__device__ __forceinline__ unsigned short f2bf(float f) {
    unsigned u = __float_as_uint(f);
    u += 0x7fff + ((u >> 16) & 1);          // RNE
    return (unsigned short)(u >> 16);
}
__device__ __forceinline__ float bf2f(unsigned short b) {
    return __uint_as_float(((unsigned)b) << 16);
}

// ---------------- CSR build ----------------
__global__ void count_kernel(const int* __restrict__ dst, int* __restrict__ cnt) {
    int e = blockIdx.x * 256 + threadIdx.x;
    if (e < NE) atomicAdd(&cnt[dst[e]], 1);
}

__global__ void chunk_sum_kernel(const int* __restrict__ cnt, int* __restrict__ csum, int n) {
    __shared__ int sdata[256];
    int base = blockIdx.x * 1024;
    int t = threadIdx.x;
    int s = 0;
    for (int i = t; i < 1024; i += 256) {
        int idx = base + i;
        if (idx < n) s += cnt[idx];
    }
    sdata[t] = s; __syncthreads();
    for (int off = 128; off > 0; off >>= 1) {
        if (t < off) sdata[t] += sdata[t + off];
        __syncthreads();
    }
    if (t == 0) csum[blockIdx.x] = sdata[0];
}

__global__ void chunk_scan_kernel(int* __restrict__ csum, int nchunks) {
    if (threadIdx.x == 0 && blockIdx.x == 0) {
        int run = 0;
        for (int i = 0; i < nchunks; i++) { int v = csum[i]; csum[i] = run; run += v; }
    }
}

__global__ void rowptr_kernel(const int* __restrict__ cnt, const int* __restrict__ coff,
                              int* __restrict__ rowptr, int n) {
    __shared__ int buf[1024];
    int t = threadIdx.x;
    int idx = blockIdx.x * 1024 + t;
    int v = (idx < n) ? cnt[idx] : 0;
    buf[t] = v; __syncthreads();
    for (int off = 1; off < 1024; off <<= 1) {
        int tmp = (t >= off) ? buf[t - off] : 0;
        __syncthreads();
        buf[t] += tmp;
        __syncthreads();
    }
    int excl = buf[t] - v + coff[blockIdx.x];
    if (idx < n) rowptr[idx] = excl;
    if (idx == n - 1) rowptr[n] = excl + v;
}

__global__ void scatter_kernel(const int* __restrict__ src, const int* __restrict__ dst,
                               const int* __restrict__ rowptr, int* __restrict__ cursor,
                               int* __restrict__ csr_src) {
    int e = blockIdx.x * 256 + threadIdx.x;
    if (e < NE) {
        int d = dst[e];
        int p = rowptr[d] + atomicAdd(&cursor[d], 1);
        csr_src[p] = src[e];
    }
}

// ---------------- W split + fragment reorder (once per layer per call) ----------------
// Wf layout: ((kb*16 + tile)*64 + lane)*16 + {j: hi, 8+j: lo}
// value(hi/lo) = split of W[kb*32 + (lane>>4)*8 + j][tile*16 + (lane&15)]
__global__ void wsplit_kernel(const float* __restrict__ W, unsigned short* __restrict__ Wf, int K) {
    int idx = blockIdx.x * 256 + threadIdx.x;
    int total = (K >> 5) * 16 * 64;
    if (idx >= total) return;
    int lane = idx & 63;
    int tile = (idx >> 6) & 15;
    int kb   = idx >> 10;
    int col  = tile * 16 + (lane & 15);
    int krow = kb * 32 + (lane >> 4) * 8;
    unsigned short* p = Wf + (size_t)idx * 16;
#pragma unroll
    for (int j = 0; j < 8; j++) {
        float v = W[(size_t)(krow + j) * HD + col];
        unsigned short h = f2bf(v);
        unsigned short l = f2bf(v - bf2f(h));
        p[j] = h;
        p[8 + j] = l;
    }
}

// ---------------- MFMA GEMM + fused el/er ----------------
// H[N,256] = X[N,K] @ W[K,256] via bf16 hi/lo split (3 MFMA products).
// Block: 128 rows x 256 cols, 4 waves; wave w owns cols [w*64, w*64+64) = head w.
// Per wave: 8 row-tiles x 4 col-tiles of 16x16x32. No LDS, no barriers.
__global__ __launch_bounds__(256) void mfma_gemm_kernel(
    const float* __restrict__ X, const unsigned short* __restrict__ Wf, int K,
    float* __restrict__ H,
    const float* __restrict__ al, const float* __restrict__ ar,
    float* __restrict__ el, float* __restrict__ er) {
    int tid = threadIdx.x;
    int w = tid >> 6;              // wave index = head
    int lane = tid & 63;
    int rowBase = blockIdx.x * 128;
    int mrow = lane & 15;          // A: m within tile; C: col within tile
    int q = lane >> 4;             // quad

    f32x4 acc[8][4];
#pragma unroll
    for (int r = 0; r < 8; r++)
#pragma unroll
        for (int c = 0; c < 4; c++) {
            f32x4 z = {0.f, 0.f, 0.f, 0.f};
            acc[r][c] = z;
        }

    short8 Ahi[8], Alo[8];

    for (int k0 = 0; k0 < K; k0 += 32) {
        // --- load + split A fragments (8 contiguous k per lane) ---
#pragma unroll
        for (int r = 0; r < 8; r++) {
            int row = rowBase + r * 16 + mrow;
            row = row < NN ? row : NN - 1;     // clamp; OOB rows never stored
            const float* xp = &X[(size_t)row * K + k0 + q * 8];
            float4 v0 = *(const float4*)xp;
            float4 v1 = *(const float4*)(xp + 4);
            float vv[8] = {v0.x, v0.y, v0.z, v0.w, v1.x, v1.y, v1.z, v1.w};
            short8 hi, lo;
#pragma unroll
            for (int j = 0; j < 8; j++) {
                unsigned short h = f2bf(vv[j]);
                unsigned short l = f2bf(vv[j] - bf2f(h));
                hi[j] = (short)h;
                lo[j] = (short)l;
            }
            Ahi[r] = hi;
            Alo[r] = lo;
        }
        // --- W fragments (pre-split, fragment-ordered) + MFMA ---
        const unsigned short* wfk =
            Wf + (((size_t)(k0 >> 5) * 16 + w * 4) * 64 + lane) * 16;
#pragma unroll
        for (int c = 0; c < 4; c++) {
            const unsigned short* wp = wfk + (size_t)c * 64 * 16;
            short8 Whi = *(const short8*)wp;
            short8 Wlo = *(const short8*)(wp + 8);
#pragma unroll
            for (int r = 0; r < 8; r++) {
                acc[r][c] = __builtin_amdgcn_mfma_f32_16x16x32_bf16(Ahi[r], Whi, acc[r][c], 0, 0, 0);
                acc[r][c] = __builtin_amdgcn_mfma_f32_16x16x32_bf16(Ahi[r], Wlo, acc[r][c], 0, 0, 0);
                acc[r][c] = __builtin_amdgcn_mfma_f32_16x16x32_bf16(Alo[r], Whi, acc[r][c], 0, 0, 0);
            }
        }
    }

    // --- epilogue: store H + fused el/er (head w) ---
    int n0 = w * 64;
    float alv[4], arv[4];
#pragma unroll
    for (int c = 0; c < 4; c++) {
        alv[c] = al[n0 + c * 16 + mrow];
        arv[c] = ar[n0 + c * 16 + mrow];
    }
#pragma unroll
    for (int r = 0; r < 8; r++) {
        float pl[4] = {0.f, 0.f, 0.f, 0.f};
        float pr[4] = {0.f, 0.f, 0.f, 0.f};
#pragma unroll
        for (int c = 0; c < 4; c++)
#pragma unroll
            for (int g = 0; g < 4; g++) {
                pl[g] += acc[r][c][g] * alv[c];
                pr[g] += acc[r][c][g] * arv[c];
            }
#pragma unroll
        for (int g = 0; g < 4; g++) {
#pragma unroll
            for (int off = 1; off < 16; off <<= 1) {
                pl[g] += __shfl_xor(pl[g], off);
                pr[g] += __shfl_xor(pr[g], off);
            }
        }
#pragma unroll
        for (int g = 0; g < 4; g++) {
            int row = rowBase + r * 16 + q * 4 + g;
            if (row < NN) {
#pragma unroll
                for (int c = 0; c < 4; c++)
                    H[(size_t)row * HD + n0 + c * 16 + mrow] = acc[r][c][g];
                if (mrow == 0) {
                    el[row * 4 + w] = pl[g];
                    er[row * 4 + w] = pr[g];
                }
            }
        }
    }
}

// ---------------- GAT per-node: single-pass flash softmax, unroll-2 ----------------
__device__ __forceinline__ float lrelu(float x) { return x > 0.f ? x : NEG_SLOPE * x; }

template <int FINAL>
__global__ __launch_bounds__(256) void gat_node_kernel(
    const float* __restrict__ H, const float* __restrict__ el, const float* __restrict__ er,
    const int* __restrict__ rowptr, const int* __restrict__ csr_src,
    float* __restrict__ out, const float* __restrict__ Wout, const float* __restrict__ bout,
    float* __restrict__ final_out) {
    int wave = threadIdx.x >> 6, lane = threadIdx.x & 63;
    int v = blockIdx.x * 4 + wave;
    if (v >= NN) return;
    int beg = rowptr[v], end = rowptr[v + 1];

    int hh = lane >> 4;                    // head for this lane's feature slice
    float er_h = er[v * 4 + hh];

    float m = -INFINITY;
    float ssum = 0.f;
    float4 acc = make_float4(0.f, 0.f, 0.f, 0.f);

    int idx = beg;
    for (; idx + 2 <= end; idx += 2) {
        int s0 = csr_src[idx];
        int s1 = csr_src[idx + 1];
        float el0 = el[s0 * 4 + hh];
        float el1 = el[s1 * 4 + hh];
        float4 h0 = *(const float4*)&H[(long)s0 * HD + lane * 4];
        float4 h1 = *(const float4*)&H[(long)s1 * HD + lane * 4];
        float e0 = lrelu(el0 + er_h);
        float e1 = lrelu(el1 + er_h);
        float mn = fmaxf(m, fmaxf(e0, e1));
        float sc = __expf(m - mn);
        float w0 = __expf(e0 - mn);
        float w1 = __expf(e1 - mn);
        ssum = ssum * sc + w0 + w1;
        acc.x = acc.x * sc + w0 * h0.x + w1 * h1.x;
        acc.y = acc.y * sc + w0 * h0.y + w1 * h1.y;
        acc.z = acc.z * sc + w0 * h0.z + w1 * h1.z;
        acc.w = acc.w * sc + w0 * h0.w + w1 * h1.w;
        m = mn;
    }
    if (idx < end) {
        int s0 = csr_src[idx];
        float el0 = el[s0 * 4 + hh];
        float4 h0 = *(const float4*)&H[(long)s0 * HD + lane * 4];
        float e0 = lrelu(el0 + er_h);
        float mn = fmaxf(m, e0);
        float sc = __expf(m - mn);
        float w0 = __expf(e0 - mn);
        ssum = ssum * sc + w0;
        acc.x = acc.x * sc + w0 * h0.x;
        acc.y = acc.y * sc + w0 * h0.y;
        acc.z = acc.z * sc + w0 * h0.z;
        acc.w = acc.w * sc + w0 * h0.w;
    }

    float inv = 1.0f / (ssum + 1e-9f);
    acc.x *= inv; acc.y *= inv; acc.z *= inv; acc.w *= inv;

    // elu
    acc.x = acc.x > 0.f ? acc.x : expm1f(acc.x);
    acc.y = acc.y > 0.f ? acc.y : expm1f(acc.y);
    acc.z = acc.z > 0.f ? acc.z : expm1f(acc.z);
    acc.w = acc.w > 0.f ? acc.w : expm1f(acc.w);

    if (!FINAL) {
        *(float4*)&out[(long)v * HD + lane * 4] = acc;
    } else {
        // mean over heads (lanes l, l^16, l^32 hold same d-range, different head)
        acc.x += __shfl_xor(acc.x, 16); acc.x += __shfl_xor(acc.x, 32);
        acc.y += __shfl_xor(acc.y, 16); acc.y += __shfl_xor(acc.y, 32);
        acc.z += __shfl_xor(acc.z, 16); acc.z += __shfl_xor(acc.z, 32);
        acc.w += __shfl_xor(acc.w, 16); acc.w += __shfl_xor(acc.w, 32);
        float4 w4 = *(const float4*)&Wout[(lane & 15) * 4];
        float p = 0.25f * (acc.x * w4.x + acc.y * w4.y + acc.z * w4.z + acc.w * w4.w);
        p += __shfl_xor(p, 1);
        p += __shfl_xor(p, 2);
        p += __shfl_xor(p, 4);
        p += __shfl_xor(p, 8);
        if (lane == 0) final_out[v] = fmaxf(p + bout[0], 0.f);
    }
}

extern "C" void kernel_launch(void* const* d_in, const int* in_sizes, int n_in,
                              void* d_out, int out_size, void* d_ws, size_t ws_size,
                              hipStream_t stream) {
    const float* x    = (const float*)d_in[0];
    const int*   src  = (const int*)d_in[1];
    const int*   dst  = (const int*)d_in[2];
    const float* W0   = (const float*)d_in[3];
    const float* al0  = (const float*)d_in[4];
    const float* ar0  = (const float*)d_in[5];
    const float* W1   = (const float*)d_in[6];
    const float* al1  = (const float*)d_in[7];
    const float* ar1  = (const float*)d_in[8];
    const float* W2   = (const float*)d_in[9];
    const float* al2  = (const float*)d_in[10];
    const float* ar2  = (const float*)d_in[11];
    const float* Wout = (const float*)d_in[12];
    const float* bout = (const float*)d_in[13];
    float* outp = (float*)d_out;

    char* ws = (char*)d_ws;
    size_t off = 0;
    auto carve = [&](size_t n) -> char* {
        char* p = ws + off;
        off += (n + 255) & ~(size_t)255;
        return p;
    };
    float* h_buf   = (float*)carve((size_t)NN * HD * 4);
    float* x_buf   = (float*)carve((size_t)NN * HD * 4);
    float* el      = (float*)carve((size_t)NN * HEADS * 4);
    float* er      = (float*)carve((size_t)NN * HEADS * 4);
    int*   cnt     = (int*)carve((size_t)NN * 4);
    int*   rowptr  = (int*)carve((size_t)(NN + 1) * 4);
    int*   csr_src = (int*)carve((size_t)NE * 4);
    int*   csum    = (int*)carve(64 * 4);
    unsigned short* Wf0 = (unsigned short*)carve((size_t)4 * 16 * 64 * 16 * 2);   // K=128
    unsigned short* Wf1 = (unsigned short*)carve((size_t)8 * 16 * 64 * 16 * 2);   // K=256
    unsigned short* Wf2 = (unsigned short*)carve((size_t)8 * 16 * 64 * 16 * 2);   // K=256

    // ---- W splits (fragment-ordered bf16 hi/lo) ----
    wsplit_kernel<<<(4 * 16 * 64 * 1 + 255) / 256 * 1, 256, 0, stream>>>(W0, Wf0, 128);
    wsplit_kernel<<<(8 * 16 * 64 + 255) / 256, 256, 0, stream>>>(W1, Wf1, 256);
    wsplit_kernel<<<(8 * 16 * 64 + 255) / 256, 256, 0, stream>>>(W2, Wf2, 256);

    // ---- build dst-CSR (same work every call) ----
    hipMemsetAsync(cnt, 0, (size_t)NN * 4, stream);
    count_kernel<<<(NE + 255) / 256, 256, 0, stream>>>(dst, cnt);
    chunk_sum_kernel<<<NCHUNK, 256, 0, stream>>>(cnt, csum, NN);
    chunk_scan_kernel<<<1, 64, 0, stream>>>(csum, NCHUNK);
    rowptr_kernel<<<NCHUNK, 1024, 0, stream>>>(cnt, csum, rowptr, NN);
    hipMemsetAsync(cnt, 0, (size_t)NN * 4, stream);
    scatter_kernel<<<(NE + 255) / 256, 256, 0, stream>>>(src, dst, rowptr, cnt, csr_src);

    int gGemm = (NN + 127) / 128;          // 391
    int gNode = (NN + 3) / 4;

    // ---- layer 0 ----
    mfma_gemm_kernel<<<gGemm, 256, 0, stream>>>(x, Wf0, 128, h_buf, al0, ar0, el, er);
    gat_node_kernel<0><<<gNode, 256, 0, stream>>>(h_buf, el, er, rowptr, csr_src,
                                                  x_buf, nullptr, nullptr, nullptr);
    // ---- layer 1 ----
    mfma_gemm_kernel<<<gGemm, 256, 0, stream>>>(x_buf, Wf1, 256, h_buf, al1, ar1, el, er);
    gat_node_kernel<0><<<gNode, 256, 0, stream>>>(h_buf, el, er, rowptr, csr_src,
                                                  x_buf, nullptr, nullptr, nullptr);
    // ---- layer 2 (final: fused elu + head-mean + Wout + relu) ----
    mfma_gemm_kernel<<<gGemm, 256, 0, stream>>>(x_buf, Wf2, 256, h_buf, al2, ar2, el, er);
    gat_node_kernel<1><<<gNode, 256, 0, stream>>>(h_buf, el, er, rowptr, csr_src,
                                                  nullptr, Wout, bout, outp);
}

// Round 6
// 674.907 us; speedup vs baseline: 1.3513x; 1.1489x over previous
//
#include <hip/hip_runtime.h>
#include <math.h>

#define NN 50000
#define NE 800000
#define HEADS 4
#define HID 64
#define HD 256          // HEADS*HID flattened feature dim
#define NEG_SLOPE 0.2f
#define NCHUNK 49       // ceil(50000/1024)

typedef __attribute__((ext_vector_type(8))) short short8;
typedef __attribute__((ext_vector_type(4))) float f32x4;

__device__ __forceinline__ unsigned short f2bf(float f) {
    unsigned u = __float_as_uint(f);
    u += 0x7fff + ((u >> 16) & 1);          // RNE
    return (unsigned short)(u >> 16);
}
__device__ __forceinline__ float bf2f(unsigned short b) {
    return __uint_as_float(((unsigned)b) << 16);
}

// ---------------- CSR build ----------------
__global__ void count_kernel(const int* __restrict__ dst, int* __restrict__ cnt) {
    int e = blockIdx.x * 256 + threadIdx.x;
    if (e < NE) atomicAdd(&cnt[dst[e]], 1);
}

__global__ void chunk_sum_kernel(const int* __restrict__ cnt, int* __restrict__ csum, int n) {
    __shared__ int sdata[256];
    int base = blockIdx.x * 1024;
    int t = threadIdx.x;
    int s = 0;
    for (int i = t; i < 1024; i += 256) {
        int idx = base + i;
        if (idx < n) s += cnt[idx];
    }
    sdata[t] = s; __syncthreads();
    for (int off = 128; off > 0; off >>= 1) {
        if (t < off) sdata[t] += sdata[t + off];
        __syncthreads();
    }
    if (t == 0) csum[blockIdx.x] = sdata[0];
}

__global__ void chunk_scan_kernel(int* __restrict__ csum, int nchunks) {
    if (threadIdx.x == 0 && blockIdx.x == 0) {
        int run = 0;
        for (int i = 0; i < nchunks; i++) { int v = csum[i]; csum[i] = run; run += v; }
    }
}

__global__ void rowptr_kernel(const int* __restrict__ cnt, const int* __restrict__ coff,
                              int* __restrict__ rowptr, int n) {
    __shared__ int buf[1024];
    int t = threadIdx.x;
    int idx = blockIdx.x * 1024 + t;
    int v = (idx < n) ? cnt[idx] : 0;
    buf[t] = v; __syncthreads();
    for (int off = 1; off < 1024; off <<= 1) {
        int tmp = (t >= off) ? buf[t - off] : 0;
        __syncthreads();
        buf[t] += tmp;
        __syncthreads();
    }
    int excl = buf[t] - v + coff[blockIdx.x];
    if (idx < n) rowptr[idx] = excl;
    if (idx == n - 1) rowptr[n] = excl + v;
}

__global__ void scatter_kernel(const int* __restrict__ src, const int* __restrict__ dst,
                               const int* __restrict__ rowptr, int* __restrict__ cursor,
                               int* __restrict__ csr_src) {
    int e = blockIdx.x * 256 + threadIdx.x;
    if (e < NE) {
        int d = dst[e];
        int p = rowptr[d] + atomicAdd(&cursor[d], 1);
        csr_src[p] = src[e];
    }
}

// ---------------- X split: fp32 -> bf16 hi/lo (layer-0 input) ----------------
__global__ void xsplit_kernel(const float* __restrict__ X, ushort* __restrict__ Xh,
                              ushort* __restrict__ Xl, int total4) {
    int i = blockIdx.x * 256 + threadIdx.x;
    if (i >= total4) return;
    float4 v = ((const float4*)X)[i];
    ushort4 h, l;
    h.x = f2bf(v.x); l.x = f2bf(v.x - bf2f(h.x));
    h.y = f2bf(v.y); l.y = f2bf(v.y - bf2f(h.y));
    h.z = f2bf(v.z); l.z = f2bf(v.z - bf2f(h.z));
    h.w = f2bf(v.w); l.w = f2bf(v.w - bf2f(h.w));
    ((ushort4*)Xh)[i] = h;
    ((ushort4*)Xl)[i] = l;
}

// ---------------- W split + fragment reorder (once per layer per call) ----------------
// Wf layout: ((kb*16 + tile)*64 + lane)*16 + {j: hi, 8+j: lo}
// value(hi/lo) = split of W[kb*32 + (lane>>4)*8 + j][tile*16 + (lane&15)]
__global__ void wsplit_kernel(const float* __restrict__ W, unsigned short* __restrict__ Wf, int K) {
    int idx = blockIdx.x * 256 + threadIdx.x;
    int total = (K >> 5) * 16 * 64;
    if (idx >= total) return;
    int lane = idx & 63;
    int tile = (idx >> 6) & 15;
    int kb   = idx >> 10;
    int col  = tile * 16 + (lane & 15);
    int krow = kb * 32 + (lane >> 4) * 8;
    unsigned short* p = Wf + (size_t)idx * 16;
#pragma unroll
    for (int j = 0; j < 8; j++) {
        float v = W[(size_t)(krow + j) * HD + col];
        unsigned short h = f2bf(v);
        unsigned short l = f2bf(v - bf2f(h));
        p[j] = h;
        p[8 + j] = l;
    }
}

// ---------------- MFMA GEMM + fused el/er ----------------
// H[N,256] = (Xhi+Xlo)[N,K] @ W[K,256], bf16 hi/lo (3 MFMA products, lo*lo dropped).
// Block: 64 rows x 256 cols, 4 waves; wave w owns head w's 64 cols.
// Per wave: 4 row-tiles x 4 col-tiles of 16x16x32. No LDS, no barriers.
__global__ __launch_bounds__(256) void mfma_gemm_kernel(
    const ushort* __restrict__ Xh, const ushort* __restrict__ Xl,
    const unsigned short* __restrict__ Wf, int K,
    float* __restrict__ H,
    const float* __restrict__ al, const float* __restrict__ ar,
    float* __restrict__ el, float* __restrict__ er) {
    int tid = threadIdx.x;
    int w = tid >> 6;              // wave index = head
    int lane = tid & 63;
    int rowBase = blockIdx.x * 64;
    int mrow = lane & 15;          // A: m within tile; C: col within tile
    int q = lane >> 4;             // quad

    f32x4 acc[4][4];
#pragma unroll
    for (int r = 0; r < 4; r++)
#pragma unroll
        for (int c = 0; c < 4; c++) {
            f32x4 z = {0.f, 0.f, 0.f, 0.f};
            acc[r][c] = z;
        }

    for (int k0 = 0; k0 < K; k0 += 32) {
        short8 Ahi[4], Alo[4];
#pragma unroll
        for (int r = 0; r < 4; r++) {
            int row = rowBase + r * 16 + mrow;
            row = row < NN ? row : NN - 1;     // clamp; OOB rows never stored
            size_t o = (size_t)row * K + k0 + q * 8;
            Ahi[r] = *(const short8*)&Xh[o];
            Alo[r] = *(const short8*)&Xl[o];
        }
        const unsigned short* wfk =
            Wf + (((size_t)(k0 >> 5) * 16 + w * 4) * 64 + lane) * 16;
#pragma unroll
        for (int c = 0; c < 4; c++) {
            const unsigned short* wp = wfk + (size_t)c * 64 * 16;
            short8 Whi = *(const short8*)wp;
            short8 Wlo = *(const short8*)(wp + 8);
#pragma unroll
            for (int r = 0; r < 4; r++) {
                acc[r][c] = __builtin_amdgcn_mfma_f32_16x16x32_bf16(Ahi[r], Whi, acc[r][c], 0, 0, 0);
                acc[r][c] = __builtin_amdgcn_mfma_f32_16x16x32_bf16(Ahi[r], Wlo, acc[r][c], 0, 0, 0);
                acc[r][c] = __builtin_amdgcn_mfma_f32_16x16x32_bf16(Alo[r], Whi, acc[r][c], 0, 0, 0);
            }
        }
    }

    // --- epilogue: store H + fused el/er (head w) ---
    int n0 = w * 64;
    float alv[4], arv[4];
#pragma unroll
    for (int c = 0; c < 4; c++) {
        alv[c] = al[n0 + c * 16 + mrow];
        arv[c] = ar[n0 + c * 16 + mrow];
    }
#pragma unroll
    for (int r = 0; r < 4; r++) {
        float pl[4] = {0.f, 0.f, 0.f, 0.f};
        float pr[4] = {0.f, 0.f, 0.f, 0.f};
#pragma unroll
        for (int c = 0; c < 4; c++)
#pragma unroll
            for (int g = 0; g < 4; g++) {
                pl[g] += acc[r][c][g] * alv[c];
                pr[g] += acc[r][c][g] * arv[c];
            }
#pragma unroll
        for (int g = 0; g < 4; g++) {
#pragma unroll
            for (int off = 1; off < 16; off <<= 1) {
                pl[g] += __shfl_xor(pl[g], off);
                pr[g] += __shfl_xor(pr[g], off);
            }
        }
#pragma unroll
        for (int g = 0; g < 4; g++) {
            int row = rowBase + r * 16 + q * 4 + g;
            if (row < NN) {
#pragma unroll
                for (int c = 0; c < 4; c++)
                    H[(size_t)row * HD + n0 + c * 16 + mrow] = acc[r][c][g];
                if (mrow == 0) {
                    el[row * 4 + w] = pl[g];
                    er[row * 4 + w] = pr[g];
                }
            }
        }
    }
}

// ---------------- GAT per-node: single-pass flash softmax, unroll-2 ----------------
__device__ __forceinline__ float lrelu(float x) { return x > 0.f ? x : NEG_SLOPE * x; }

template <int FINAL>
__global__ __launch_bounds__(256) void gat_node_kernel(
    const float* __restrict__ H, const float* __restrict__ el, const float* __restrict__ er,
    const int* __restrict__ rowptr, const int* __restrict__ csr_src,
    ushort* __restrict__ out_hi, ushort* __restrict__ out_lo,
    const float* __restrict__ Wout, const float* __restrict__ bout,
    float* __restrict__ final_out) {
    int wave = threadIdx.x >> 6, lane = threadIdx.x & 63;
    int v = blockIdx.x * 4 + wave;
    if (v >= NN) return;
    int beg = rowptr[v], end = rowptr[v + 1];

    int hh = lane >> 4;                    // head for this lane's feature slice
    float er_h = er[v * 4 + hh];

    float m = -INFINITY;
    float ssum = 0.f;
    float4 acc = make_float4(0.f, 0.f, 0.f, 0.f);

    int idx = beg;
    for (; idx + 2 <= end; idx += 2) {
        int s0 = csr_src[idx];
        int s1 = csr_src[idx + 1];
        float el0 = el[s0 * 4 + hh];
        float el1 = el[s1 * 4 + hh];
        float4 h0 = *(const float4*)&H[(long)s0 * HD + lane * 4];
        float4 h1 = *(const float4*)&H[(long)s1 * HD + lane * 4];
        float e0 = lrelu(el0 + er_h);
        float e1 = lrelu(el1 + er_h);
        float mn = fmaxf(m, fmaxf(e0, e1));
        float sc = __expf(m - mn);
        float w0 = __expf(e0 - mn);
        float w1 = __expf(e1 - mn);
        ssum = ssum * sc + w0 + w1;
        acc.x = acc.x * sc + w0 * h0.x + w1 * h1.x;
        acc.y = acc.y * sc + w0 * h0.y + w1 * h1.y;
        acc.z = acc.z * sc + w0 * h0.z + w1 * h1.z;
        acc.w = acc.w * sc + w0 * h0.w + w1 * h1.w;
        m = mn;
    }
    if (idx < end) {
        int s0 = csr_src[idx];
        float el0 = el[s0 * 4 + hh];
        float4 h0 = *(const float4*)&H[(long)s0 * HD + lane * 4];
        float e0 = lrelu(el0 + er_h);
        float mn = fmaxf(m, e0);
        float sc = __expf(m - mn);
        float w0 = __expf(e0 - mn);
        ssum = ssum * sc + w0;
        acc.x = acc.x * sc + w0 * h0.x;
        acc.y = acc.y * sc + w0 * h0.y;
        acc.z = acc.z * sc + w0 * h0.z;
        acc.w = acc.w * sc + w0 * h0.w;
    }

    float inv = 1.0f / (ssum + 1e-9f);
    acc.x *= inv; acc.y *= inv; acc.z *= inv; acc.w *= inv;

    // elu
    acc.x = acc.x > 0.f ? acc.x : expm1f(acc.x);
    acc.y = acc.y > 0.f ? acc.y : expm1f(acc.y);
    acc.z = acc.z > 0.f ? acc.z : expm1f(acc.z);
    acc.w = acc.w > 0.f ? acc.w : expm1f(acc.w);

    if (!FINAL) {
        // write hi/lo bf16 split (next GEMM's A operand) — same values as fp32 path
        ushort4 hv, lv;
        hv.x = f2bf(acc.x); lv.x = f2bf(acc.x - bf2f(hv.x));
        hv.y = f2bf(acc.y); lv.y = f2bf(acc.y - bf2f(hv.y));
        hv.z = f2bf(acc.z); lv.z = f2bf(acc.z - bf2f(hv.z));
        hv.w = f2bf(acc.w); lv.w = f2bf(acc.w - bf2f(hv.w));
        *(ushort4*)&out_hi[(size_t)v * HD + lane * 4] = hv;
        *(ushort4*)&out_lo[(size_t)v * HD + lane * 4] = lv;
    } else {
        // mean over heads (lanes l, l^16, l^32 hold same d-range, different head)
        acc.x += __shfl_xor(acc.x, 16); acc.x += __shfl_xor(acc.x, 32);
        acc.y += __shfl_xor(acc.y, 16); acc.y += __shfl_xor(acc.y, 32);
        acc.z += __shfl_xor(acc.z, 16); acc.z += __shfl_xor(acc.z, 32);
        acc.w += __shfl_xor(acc.w, 16); acc.w += __shfl_xor(acc.w, 32);
        float4 w4 = *(const float4*)&Wout[(lane & 15) * 4];
        float p = 0.25f * (acc.x * w4.x + acc.y * w4.y + acc.z * w4.z + acc.w * w4.w);
        p += __shfl_xor(p, 1);
        p += __shfl_xor(p, 2);
        p += __shfl_xor(p, 4);
        p += __shfl_xor(p, 8);
        if (lane == 0) final_out[v] = fmaxf(p + bout[0], 0.f);
    }
}

extern "C" void kernel_launch(void* const* d_in, const int* in_sizes, int n_in,
                              void* d_out, int out_size, void* d_ws, size_t ws_size,
                              hipStream_t stream) {
    const float* x    = (const float*)d_in[0];
    const int*   src  = (const int*)d_in[1];
    const int*   dst  = (const int*)d_in[2];
    const float* W0   = (const float*)d_in[3];
    const float* al0  = (const float*)d_in[4];
    const float* ar0  = (const float*)d_in[5];
    const float* W1   = (const float*)d_in[6];
    const float* al1  = (const float*)d_in[7];
    const float* ar1  = (const float*)d_in[8];
    const float* W2   = (const float*)d_in[9];
    const float* al2  = (const float*)d_in[10];
    const float* ar2  = (const float*)d_in[11];
    const float* Wout = (const float*)d_in[12];
    const float* bout = (const float*)d_in[13];
    float* outp = (float*)d_out;

    char* ws = (char*)d_ws;
    size_t off = 0;
    auto carve = [&](size_t n) -> char* {
        char* p = ws + off;
        off += (n + 255) & ~(size_t)255;
        return p;
    };
    float*  h_buf  = (float*)carve((size_t)NN * HD * 4);
    ushort* xh     = (ushort*)carve((size_t)NN * HD * 2);   // A hi (K<=256)
    ushort* xl     = (ushort*)carve((size_t)NN * HD * 2);   // A lo
    float*  el     = (float*)carve((size_t)NN * HEADS * 4);
    float*  er     = (float*)carve((size_t)NN * HEADS * 4);
    int*    cnt    = (int*)carve((size_t)NN * 4);
    int*    rowptr = (int*)carve((size_t)(NN + 1) * 4);
    int*    csr_src= (int*)carve((size_t)NE * 4);
    int*    csum   = (int*)carve(64 * 4);
    unsigned short* Wf0 = (unsigned short*)carve((size_t)4 * 16 * 64 * 16 * 2);   // K=128
    unsigned short* Wf1 = (unsigned short*)carve((size_t)8 * 16 * 64 * 16 * 2);   // K=256
    unsigned short* Wf2 = (unsigned short*)carve((size_t)8 * 16 * 64 * 16 * 2);   // K=256

    // ---- W splits (fragment-ordered bf16 hi/lo) ----
    wsplit_kernel<<<(4 * 16 * 64 + 255) / 256, 256, 0, stream>>>(W0, Wf0, 128);
    wsplit_kernel<<<(8 * 16 * 64 + 255) / 256, 256, 0, stream>>>(W1, Wf1, 256);
    wsplit_kernel<<<(8 * 16 * 64 + 255) / 256, 256, 0, stream>>>(W2, Wf2, 256);
    // ---- layer-0 input split (N x 128, row stride 128) ----
    xsplit_kernel<<<(NN * 128 / 4 + 255) / 256, 256, 0, stream>>>(x, xh, xl, NN * 128 / 4);

    // ---- build dst-CSR (same work every call) ----
    hipMemsetAsync(cnt, 0, (size_t)NN * 4, stream);
    count_kernel<<<(NE + 255) / 256, 256, 0, stream>>>(dst, cnt);
    chunk_sum_kernel<<<NCHUNK, 256, 0, stream>>>(cnt, csum, NN);
    chunk_scan_kernel<<<1, 64, 0, stream>>>(csum, NCHUNK);
    rowptr_kernel<<<NCHUNK, 1024, 0, stream>>>(cnt, csum, rowptr, NN);
    hipMemsetAsync(cnt, 0, (size_t)NN * 4, stream);
    scatter_kernel<<<(NE + 255) / 256, 256, 0, stream>>>(src, dst, rowptr, cnt, csr_src);

    int gGemm = (NN + 63) / 64;            // 782
    int gNode = (NN + 3) / 4;

    // ---- layer 0 ----
    mfma_gemm_kernel<<<gGemm, 256, 0, stream>>>(xh, xl, Wf0, 128, h_buf, al0, ar0, el, er);
    gat_node_kernel<0><<<gNode, 256, 0, stream>>>(h_buf, el, er, rowptr, csr_src,
                                                  xh, xl, nullptr, nullptr, nullptr);
    // ---- layer 1 ----
    mfma_gemm_kernel<<<gGemm, 256, 0, stream>>>(xh, xl, Wf1, 256, h_buf, al1, ar1, el, er);
    gat_node_kernel<0><<<gNode, 256, 0, stream>>>(h_buf, el, er, rowptr, csr_src,
                                                  xh, xl, nullptr, nullptr, nullptr);
    // ---- layer 2 (final: fused elu + head-mean + Wout + relu) ----
    mfma_gemm_kernel<<<gGemm, 256, 0, stream>>>(xh, xl, Wf2, 256, h_buf, al2, ar2, el, er);
    gat_node_kernel<1><<<gNode, 256, 0, stream>>>(h_buf, el, er, rowptr, csr_src,
                                                  nullptr, nullptr, Wout, bout, outp);
}

// Round 7
// 664.965 us; speedup vs baseline: 1.3715x; 1.0150x over previous
//
#include <hip/hip_runtime.h>
#include <math.h>

#define NN 50000
#define NE 800000
#define HEADS 4
#define HID 64
#define HD 256          // HEADS*HID flattened feature dim
#define NEG_SLOPE 0.2f
#define NCHUNK 49       // ceil(50000/1024)

typedef __attribute__((ext_vector_type(8))) short short8;
typedef __attribute__((ext_vector_type(4))) float f32x4;

__device__ __forceinline__ unsigned short f2bf(float f) {
    unsigned u = __float_as_uint(f);
    u += 0x7fff + ((u >> 16) & 1);          // RNE
    return (unsigned short)(u >> 16);
}
__device__ __forceinline__ float bf2f(unsigned short b) {
    return __uint_as_float(((unsigned)b) << 16);
}

// ---------------- CSR build ----------------
__global__ void count_kernel(const int* __restrict__ dst, int* __restrict__ cnt) {
    int e = blockIdx.x * 256 + threadIdx.x;
    if (e < NE) atomicAdd(&cnt[dst[e]], 1);
}

__global__ void chunk_sum_kernel(const int* __restrict__ cnt, int* __restrict__ csum, int n) {
    __shared__ int sdata[256];
    int base = blockIdx.x * 1024;
    int t = threadIdx.x;
    int s = 0;
    for (int i = t; i < 1024; i += 256) {
        int idx = base + i;
        if (idx < n) s += cnt[idx];
    }
    sdata[t] = s; __syncthreads();
    for (int off = 128; off > 0; off >>= 1) {
        if (t < off) sdata[t] += sdata[t + off];
        __syncthreads();
    }
    if (t == 0) csum[blockIdx.x] = sdata[0];
}

// rowptr + cursor-init; chunk offset computed in-block from csum (no separate scan pass)
__global__ void rowptr_kernel(const int* __restrict__ cnt, const int* __restrict__ csum,
                              int* __restrict__ rowptr, int* __restrict__ cursor, int n) {
    __shared__ int buf[1024];
    __shared__ int chunkOff;
    int t = threadIdx.x;
    int idx = blockIdx.x * 1024 + t;
    // exclusive offset of this chunk = sum of csum[0..bid)
    if (t < 64) {
        int partial = 0;
        for (int i = t; i < blockIdx.x; i += 64) partial += csum[i];
#pragma unroll
        for (int off = 32; off > 0; off >>= 1) partial += __shfl_down(partial, off);
        if (t == 0) chunkOff = partial;
    }
    int v = (idx < n) ? cnt[idx] : 0;
    buf[t] = v; __syncthreads();
    for (int off = 1; off < 1024; off <<= 1) {
        int tmp = (t >= off) ? buf[t - off] : 0;
        __syncthreads();
        buf[t] += tmp;
        __syncthreads();
    }
    int excl = buf[t] - v + chunkOff;
    if (idx < n) { rowptr[idx] = excl; cursor[idx] = excl; }
    if (idx == n - 1) rowptr[n] = excl + v;
}

__global__ void scatter_kernel(const int* __restrict__ src, const int* __restrict__ dst,
                               int* __restrict__ cursor, int* __restrict__ csr_src) {
    int e = blockIdx.x * 256 + threadIdx.x;
    if (e < NE) {
        int p = atomicAdd(&cursor[dst[e]], 1);
        csr_src[p] = src[e];
    }
}

// ---------------- X split: fp32 -> bf16 hi/lo (layer-0 input) ----------------
__global__ void xsplit_kernel(const float* __restrict__ X, ushort* __restrict__ Xh,
                              ushort* __restrict__ Xl, int total4) {
    int i = blockIdx.x * 256 + threadIdx.x;
    if (i >= total4) return;
    float4 v = ((const float4*)X)[i];
    ushort4 h, l;
    h.x = f2bf(v.x); l.x = f2bf(v.x - bf2f(h.x));
    h.y = f2bf(v.y); l.y = f2bf(v.y - bf2f(h.y));
    h.z = f2bf(v.z); l.z = f2bf(v.z - bf2f(h.z));
    h.w = f2bf(v.w); l.w = f2bf(v.w - bf2f(h.w));
    ((ushort4*)Xh)[i] = h;
    ((ushort4*)Xl)[i] = l;
}

// ---------------- W split + fragment reorder, all 3 layers in one dispatch ----------------
// Wf layout: ((kb*16 + tile)*64 + lane)*16 + {j: hi, 8+j: lo}
__device__ __forceinline__ void wsplit_one(const float* W, unsigned short* Wf, int idx) {
    int lane = idx & 63;
    int tile = (idx >> 6) & 15;
    int kb   = idx >> 10;
    int col  = tile * 16 + (lane & 15);
    int krow = kb * 32 + (lane >> 4) * 8;
    unsigned short* p = Wf + (size_t)idx * 16;
#pragma unroll
    for (int j = 0; j < 8; j++) {
        float v = W[(size_t)(krow + j) * HD + col];
        unsigned short h = f2bf(v);
        unsigned short l = f2bf(v - bf2f(h));
        p[j] = h;
        p[8 + j] = l;
    }
}

__global__ void wsplit_all_kernel(const float* __restrict__ W0, unsigned short* __restrict__ Wf0,
                                  const float* __restrict__ W1, unsigned short* __restrict__ Wf1,
                                  const float* __restrict__ W2, unsigned short* __restrict__ Wf2) {
    int idx = blockIdx.x * 256 + threadIdx.x;
    const int n0 = 4 * 16 * 64;            // K=128
    const int n1 = 8 * 16 * 64;            // K=256
    if (idx < n0) wsplit_one(W0, Wf0, idx);
    else if (idx < n0 + n1) wsplit_one(W1, Wf1, idx - n0);
    else if (idx < n0 + 2 * n1) wsplit_one(W2, Wf2, idx - n0 - n1);
}

// ---------------- MFMA GEMM + fused el/er, ping-pong register pipeline ----------------
// H[N,256] = (Xhi+Xlo)[N,K] @ W[K,256], bf16 hi/lo (3 MFMA products, lo*lo dropped).
// Block: 64 rows x 256 cols, 4 waves; wave w owns head w's 64 cols.
__global__ __launch_bounds__(256, 2) void mfma_gemm_kernel(
    const ushort* __restrict__ Xh, const ushort* __restrict__ Xl,
    const unsigned short* __restrict__ Wf, int K,
    float* __restrict__ H,
    const float* __restrict__ al, const float* __restrict__ ar,
    float* __restrict__ el, float* __restrict__ er) {
    int tid = threadIdx.x;
    int w = tid >> 6;              // wave index = head
    int lane = tid & 63;
    int rowBase = blockIdx.x * 64;
    int mrow = lane & 15;          // A: m within tile; C: col within tile
    int q = lane >> 4;             // quad

    f32x4 acc[4][4];
#pragma unroll
    for (int r = 0; r < 4; r++)
#pragma unroll
        for (int c = 0; c < 4; c++) {
            f32x4 z = {0.f, 0.f, 0.f, 0.f};
            acc[r][c] = z;
        }

    auto loadA = [&](int k0, short8* AH, short8* AL) {
#pragma unroll
        for (int r = 0; r < 4; r++) {
            int row = rowBase + r * 16 + mrow;
            row = row < NN ? row : NN - 1;     // clamp; OOB rows never stored
            size_t o = (size_t)row * K + k0 + q * 8;
            AH[r] = *(const short8*)&Xh[o];
            AL[r] = *(const short8*)&Xl[o];
        }
    };
    auto loadW = [&](int k0, short8* WH, short8* WL) {
        const unsigned short* wfk =
            Wf + (((size_t)(k0 >> 5) * 16 + w * 4) * 64 + lane) * 16;
#pragma unroll
        for (int c = 0; c < 4; c++) {
            WH[c] = *(const short8*)(wfk + (size_t)c * 64 * 16);
            WL[c] = *(const short8*)(wfk + (size_t)c * 64 * 16 + 8);
        }
    };
    auto compute = [&](short8* AH, short8* AL, short8* WH, short8* WL) {
#pragma unroll
        for (int c = 0; c < 4; c++)
#pragma unroll
            for (int r = 0; r < 4; r++) {
                acc[r][c] = __builtin_amdgcn_mfma_f32_16x16x32_bf16(AH[r], WH[c], acc[r][c], 0, 0, 0);
                acc[r][c] = __builtin_amdgcn_mfma_f32_16x16x32_bf16(AH[r], WL[c], acc[r][c], 0, 0, 0);
                acc[r][c] = __builtin_amdgcn_mfma_f32_16x16x32_bf16(AL[r], WH[c], acc[r][c], 0, 0, 0);
            }
    };

    short8 Ah0[4], Al0[4], Wh0[4], Wl0[4];
    short8 Ah1[4], Al1[4], Wh1[4], Wl1[4];

    loadA(0, Ah0, Al0); loadW(0, Wh0, Wl0);
    for (int k0 = 0; k0 < K; k0 += 64) {
        loadA(k0 + 32, Ah1, Al1); loadW(k0 + 32, Wh1, Wl1);   // prefetch (K % 64 == 0)
        compute(Ah0, Al0, Wh0, Wl0);
        if (k0 + 64 < K) { loadA(k0 + 64, Ah0, Al0); loadW(k0 + 64, Wh0, Wl0); }
        compute(Ah1, Al1, Wh1, Wl1);
    }

    // --- epilogue: store H + fused el/er (head w) ---
    int n0 = w * 64;
    float alv[4], arv[4];
#pragma unroll
    for (int c = 0; c < 4; c++) {
        alv[c] = al[n0 + c * 16 + mrow];
        arv[c] = ar[n0 + c * 16 + mrow];
    }
#pragma unroll
    for (int r = 0; r < 4; r++) {
        float pl[4] = {0.f, 0.f, 0.f, 0.f};
        float pr[4] = {0.f, 0.f, 0.f, 0.f};
#pragma unroll
        for (int c = 0; c < 4; c++)
#pragma unroll
            for (int g = 0; g < 4; g++) {
                pl[g] += acc[r][c][g] * alv[c];
                pr[g] += acc[r][c][g] * arv[c];
            }
#pragma unroll
        for (int g = 0; g < 4; g++) {
#pragma unroll
            for (int off = 1; off < 16; off <<= 1) {
                pl[g] += __shfl_xor(pl[g], off);
                pr[g] += __shfl_xor(pr[g], off);
            }
        }
#pragma unroll
        for (int g = 0; g < 4; g++) {
            int row = rowBase + r * 16 + q * 4 + g;
            if (row < NN) {
#pragma unroll
                for (int c = 0; c < 4; c++)
                    H[(size_t)row * HD + n0 + c * 16 + mrow] = acc[r][c][g];
                if (mrow == 0) {
                    el[row * 4 + w] = pl[g];
                    er[row * 4 + w] = pr[g];
                }
            }
        }
    }
}

// ---------------- GAT per-node: single-pass flash softmax, unroll-2 ----------------
__device__ __forceinline__ float lrelu(float x) { return x > 0.f ? x : NEG_SLOPE * x; }

template <int FINAL>
__global__ __launch_bounds__(256) void gat_node_kernel(
    const float* __restrict__ H, const float* __restrict__ el, const float* __restrict__ er,
    const int* __restrict__ rowptr, const int* __restrict__ csr_src,
    ushort* __restrict__ out_hi, ushort* __restrict__ out_lo,
    const float* __restrict__ Wout, const float* __restrict__ bout,
    float* __restrict__ final_out) {
    int wave = threadIdx.x >> 6, lane = threadIdx.x & 63;
    int v = blockIdx.x * 4 + wave;
    if (v >= NN) return;
    int beg = rowptr[v], end = rowptr[v + 1];

    int hh = lane >> 4;                    // head for this lane's feature slice
    float er_h = er[v * 4 + hh];

    float m = -INFINITY;
    float ssum = 0.f;
    float4 acc = make_float4(0.f, 0.f, 0.f, 0.f);

    int idx = beg;
    for (; idx + 2 <= end; idx += 2) {
        int s0 = csr_src[idx];
        int s1 = csr_src[idx + 1];
        float el0 = el[s0 * 4 + hh];
        float el1 = el[s1 * 4 + hh];
        float4 h0 = *(const float4*)&H[(long)s0 * HD + lane * 4];
        float4 h1 = *(const float4*)&H[(long)s1 * HD + lane * 4];
        float e0 = lrelu(el0 + er_h);
        float e1 = lrelu(el1 + er_h);
        float mn = fmaxf(m, fmaxf(e0, e1));
        float sc = __expf(m - mn);
        float w0 = __expf(e0 - mn);
        float w1 = __expf(e1 - mn);
        ssum = ssum * sc + w0 + w1;
        acc.x = acc.x * sc + w0 * h0.x + w1 * h1.x;
        acc.y = acc.y * sc + w0 * h0.y + w1 * h1.y;
        acc.z = acc.z * sc + w0 * h0.z + w1 * h1.z;
        acc.w = acc.w * sc + w0 * h0.w + w1 * h1.w;
        m = mn;
    }
    if (idx < end) {
        int s0 = csr_src[idx];
        float el0 = el[s0 * 4 + hh];
        float4 h0 = *(const float4*)&H[(long)s0 * HD + lane * 4];
        float e0 = lrelu(el0 + er_h);
        float mn = fmaxf(m, e0);
        float sc = __expf(m - mn);
        float w0 = __expf(e0 - mn);
        ssum = ssum * sc + w0;
        acc.x = acc.x * sc + w0 * h0.x;
        acc.y = acc.y * sc + w0 * h0.y;
        acc.z = acc.z * sc + w0 * h0.z;
        acc.w = acc.w * sc + w0 * h0.w;
    }

    float inv = 1.0f / (ssum + 1e-9f);
    acc.x *= inv; acc.y *= inv; acc.z *= inv; acc.w *= inv;

    // elu
    acc.x = acc.x > 0.f ? acc.x : expm1f(acc.x);
    acc.y = acc.y > 0.f ? acc.y : expm1f(acc.y);
    acc.z = acc.z > 0.f ? acc.z : expm1f(acc.z);
    acc.w = acc.w > 0.f ? acc.w : expm1f(acc.w);

    if (!FINAL) {
        // write hi/lo bf16 split (next GEMM's A operand) — same values as fp32 path
        ushort4 hv, lv;
        hv.x = f2bf(acc.x); lv.x = f2bf(acc.x - bf2f(hv.x));
        hv.y = f2bf(acc.y); lv.y = f2bf(acc.y - bf2f(hv.y));
        hv.z = f2bf(acc.z); lv.z = f2bf(acc.z - bf2f(hv.z));
        hv.w = f2bf(acc.w); lv.w = f2bf(acc.w - bf2f(hv.w));
        *(ushort4*)&out_hi[(size_t)v * HD + lane * 4] = hv;
        *(ushort4*)&out_lo[(size_t)v * HD + lane * 4] = lv;
    } else {
        // mean over heads (lanes l, l^16, l^32 hold same d-range, different head)
        acc.x += __shfl_xor(acc.x, 16); acc.x += __shfl_xor(acc.x, 32);
        acc.y += __shfl_xor(acc.y, 16); acc.y += __shfl_xor(acc.y, 32);
        acc.z += __shfl_xor(acc.z, 16); acc.z += __shfl_xor(acc.z, 32);
        acc.w += __shfl_xor(acc.w, 16); acc.w += __shfl_xor(acc.w, 32);
        float4 w4 = *(const float4*)&Wout[(lane & 15) * 4];
        float p = 0.25f * (acc.x * w4.x + acc.y * w4.y + acc.z * w4.z + acc.w * w4.w);
        p += __shfl_xor(p, 1);
        p += __shfl_xor(p, 2);
        p += __shfl_xor(p, 4);
        p += __shfl_xor(p, 8);
        if (lane == 0) final_out[v] = fmaxf(p + bout[0], 0.f);
    }
}

extern "C" void kernel_launch(void* const* d_in, const int* in_sizes, int n_in,
                              void* d_out, int out_size, void* d_ws, size_t ws_size,
                              hipStream_t stream) {
    const float* x    = (const float*)d_in[0];
    const int*   src  = (const int*)d_in[1];
    const int*   dst  = (const int*)d_in[2];
    const float* W0   = (const float*)d_in[3];
    const float* al0  = (const float*)d_in[4];
    const float* ar0  = (const float*)d_in[5];
    const float* W1   = (const float*)d_in[6];
    const float* al1  = (const float*)d_in[7];
    const float* ar1  = (const float*)d_in[8];
    const float* W2   = (const float*)d_in[9];
    const float* al2  = (const float*)d_in[10];
    const float* ar2  = (const float*)d_in[11];
    const float* Wout = (const float*)d_in[12];
    const float* bout = (const float*)d_in[13];
    float* outp = (float*)d_out;

    char* ws = (char*)d_ws;
    size_t off = 0;
    auto carve = [&](size_t n) -> char* {
        char* p = ws + off;
        off += (n + 255) & ~(size_t)255;
        return p;
    };
    float*  h_buf  = (float*)carve((size_t)NN * HD * 4);
    ushort* xh     = (ushort*)carve((size_t)NN * HD * 2);   // A hi (K<=256)
    ushort* xl     = (ushort*)carve((size_t)NN * HD * 2);   // A lo
    float*  el     = (float*)carve((size_t)NN * HEADS * 4);
    float*  er     = (float*)carve((size_t)NN * HEADS * 4);
    int*    cnt    = (int*)carve((size_t)NN * 4);
    int*    cursor = (int*)carve((size_t)NN * 4);
    int*    rowptr = (int*)carve((size_t)(NN + 1) * 4);
    int*    csr_src= (int*)carve((size_t)NE * 4);
    int*    csum   = (int*)carve(64 * 4);
    unsigned short* Wf0 = (unsigned short*)carve((size_t)4 * 16 * 64 * 16 * 2);   // K=128
    unsigned short* Wf1 = (unsigned short*)carve((size_t)8 * 16 * 64 * 16 * 2);   // K=256
    unsigned short* Wf2 = (unsigned short*)carve((size_t)8 * 16 * 64 * 16 * 2);   // K=256

    // ---- W splits (all 3 layers, one dispatch) + layer-0 input split ----
    wsplit_all_kernel<<<(20 * 16 * 64 + 255) / 256, 256, 0, stream>>>(W0, Wf0, W1, Wf1, W2, Wf2);
    xsplit_kernel<<<(NN * 128 / 4 + 255) / 256, 256, 0, stream>>>(x, xh, xl, NN * 128 / 4);

    // ---- build dst-CSR: memset, count, chunk_sum, rowptr(+cursor), scatter ----
    hipMemsetAsync(cnt, 0, (size_t)NN * 4, stream);
    count_kernel<<<(NE + 255) / 256, 256, 0, stream>>>(dst, cnt);
    chunk_sum_kernel<<<NCHUNK, 256, 0, stream>>>(cnt, csum, NN);
    rowptr_kernel<<<NCHUNK, 1024, 0, stream>>>(cnt, csum, rowptr, cursor, NN);
    scatter_kernel<<<(NE + 255) / 256, 256, 0, stream>>>(src, dst, cursor, csr_src);

    int gGemm = (NN + 63) / 64;            // 782
    int gNode = (NN + 3) / 4;

    // ---- layer 0 ----
    mfma_gemm_kernel<<<gGemm, 256, 0, stream>>>(xh, xl, Wf0, 128, h_buf, al0, ar0, el, er);
    gat_node_kernel<0><<<gNode, 256, 0, stream>>>(h_buf, el, er, rowptr, csr_src,
                                                  xh, xl, nullptr, nullptr, nullptr);
    // ---- layer 1 ----
    mfma_gemm_kernel<<<gGemm, 256, 0, stream>>>(xh, xl, Wf1, 256, h_buf, al1, ar1, el, er);
    gat_node_kernel<0><<<gNode, 256, 0, stream>>>(h_buf, el, er, rowptr, csr_src,
                                                  xh, xl, nullptr, nullptr, nullptr);
    // ---- layer 2 (final: fused elu + head-mean + Wout + relu) ----
    mfma_gemm_kernel<<<gGemm, 256, 0, stream>>>(xh, xl, Wf2, 256, h_buf, al2, ar2, el, er);
    gat_node_kernel<1><<<gNode, 256, 0, stream>>>(h_buf, el, er, rowptr, csr_src,
                                                  nullptr, nullptr, Wout, bout, outp);
}